// Round 9
// baseline (633.962 us; speedup 1.0000x reference)
//
#include <hip/hip_runtime.h>
#include <hip/hip_bf16.h>

#define NN 50000
#define HD 128
#define NL 4
#define BN_EPS 1e-5f
#define NTILES 3125
#define N4 200000
#define GBLK 256
#define GROWS 196

typedef __attribute__((ext_vector_type(8))) short short8;
typedef __attribute__((ext_vector_type(4))) float f32x4;

__device__ inline ushort f2bf(float f){
  uint u = __float_as_uint(f);
  uint r = (u + 0x7fffu + ((u >> 16) & 1u)) >> 16;
  return (ushort)r;
}
__device__ inline float bflo(uint u){ return __uint_as_float(u << 16); }
__device__ inline float bfhi(uint u){ return __uint_as_float(u & 0xffff0000u); }

// ---------------- casts ----------------
__global__ void cast_f32_bf16x4(const float* __restrict__ in, ushort* __restrict__ out, int n4){
  int i = blockIdx.x * blockDim.x + threadIdx.x;
  int stride = gridDim.x * blockDim.x;
  const float4* in4 = (const float4*)in;
  for (; i < n4; i += stride){
    float4 v = in4[i];
    ushort4 r;
    r.x = f2bf(v.x); r.y = f2bf(v.y); r.z = f2bf(v.z); r.w = f2bf(v.w);
    *(ushort4*)(out + i * 4) = r;
  }
}

__global__ void cast_weights(const float* __restrict__ w1, const float* __restrict__ w2,
                             const float* __restrict__ wf, ushort* __restrict__ wb){
  int i = blockIdx.x * 256 + threadIdx.x;
  if (i >= 36864) return;
  const float* src;
  if (i < 16384)      src = w1 + i * 4;
  else if (i < 32768) src = w2 + (i - 16384) * 4;
  else                src = wf + (i - 32768) * 4;
  float4 v = *(const float4*)src;
  ushort4 r;
  r.x = f2bf(v.x); r.y = f2bf(v.y); r.z = f2bf(v.z); r.w = f2bf(v.w);
  *(ushort4*)(wb + i * 4) = r;
}

// ---------------- CSR build with 4 sub-counters per node ----------------
__global__ void fill1_kernel(const int* __restrict__ dst, int* __restrict__ cnt4,
                             int* __restrict__ pos, int E){
  int e = (blockIdx.x * 256 + threadIdx.x) * 4;
  if (e + 4 <= E){
    int4 d = *(const int4*)(dst + e);
    int4 p;
    p.x = atomicAdd(&cnt4[d.x * 4 + 0], 1);
    p.y = atomicAdd(&cnt4[d.y * 4 + 1], 1);
    p.z = atomicAdd(&cnt4[d.z * 4 + 2], 1);
    p.w = atomicAdd(&cnt4[d.w * 4 + 3], 1);
    *(int4*)(pos + e) = p;
  } else {
    for (; e < E; ++e) pos[e] = atomicAdd(&cnt4[dst[e] * 4 + (e & 3)], 1);
  }
}

__global__ void scan1_kernel(const int* __restrict__ deg, int* __restrict__ incl,
                             int* __restrict__ bsum, int n){
  __shared__ int tmp[1024];
  int gid = blockIdx.x * 1024 + threadIdx.x;
  int v = (gid < n) ? deg[gid] : 0;
  tmp[threadIdx.x] = v;
  __syncthreads();
  for (int ofs = 1; ofs < 1024; ofs <<= 1){
    int t = tmp[threadIdx.x];
    int a = (threadIdx.x >= ofs) ? tmp[threadIdx.x - ofs] : 0;
    __syncthreads();
    tmp[threadIdx.x] = t + a;
    __syncthreads();
  }
  if (gid < n) incl[gid] = tmp[threadIdx.x];
  if (threadIdx.x == 1023) bsum[blockIdx.x] = tmp[1023];
}

__global__ void scan2_kernel(const int* __restrict__ bsum, int* __restrict__ base,
                             int* __restrict__ off, int nb, int n){
  if (threadIdx.x == 0){
    int run = 0;
    for (int i = 0; i < nb; ++i){ base[i] = run; run += bsum[i]; }
    off[n] = run;
  }
}

__global__ void scan3_kernel(const int* __restrict__ deg, const int* __restrict__ incl,
                             const int* __restrict__ base, int* __restrict__ off, int n){
  int gid = blockIdx.x * 1024 + threadIdx.x;
  if (gid < n) off[gid] = incl[gid] - deg[gid] + base[blockIdx.x];
}

__global__ void fill2_kernel(const int* __restrict__ src, const int* __restrict__ dst,
                             const int* __restrict__ off4, const int* __restrict__ pos,
                             int* __restrict__ csrc, int E){
  int e = (blockIdx.x * 256 + threadIdx.x) * 4;
  if (e + 4 <= E){
    int4 d = *(const int4*)(dst + e);
    int4 p = *(const int4*)(pos + e);
    int4 s = *(const int4*)(src + e);
    csrc[off4[d.x * 4 + 0] + p.x] = s.x;
    csrc[off4[d.y * 4 + 1] + p.y] = s.y;
    csrc[off4[d.z * 4 + 2] + p.z] = s.z;
    csrc[off4[d.w * 4 + 3] + p.w] = s.w;
  } else {
    for (; e < E; ++e) csrc[off4[dst[e] * 4 + (e & 3)] + pos[e]] = src[e];
  }
}

// ---------------- BN param helper ----------------
__device__ inline void bn_params_tid(const float* st, const float* gA, const float* gB,
                                     const float* bB, int mode, float* sS, float* sT){
  int c = threadIdx.x;
  if (c < 128){
    const float invN = 1.f / (float)NN;
    float mu = st[c] * invN;
    float var = fmaxf(st[128 + c] * invN - mu * mu, 0.f);
    float S, T;
    if (mode == 0){
      S = gA[c] * rsqrtf(var + BN_EPS);
      T = gB[c] - mu * S;
    } else {
      float inv2 = rsqrtf(var + BN_EPS);
      float tt = gA[c] * inv2;
      float inv3 = rsqrtf(tt * tt * var + BN_EPS);
      S = tt * inv3 * gB[c];
      T = bB[c] - mu * S;
    }
    sS[c] = S; sT[c] = T;
  }
}

// ---------------- aggregation, layer 0 ----------------
__global__ __launch_bounds__(256) void agg_kernel(const ushort* __restrict__ xb,
                                                  const int* __restrict__ off4,
                                                  const int* __restrict__ csrc,
                                                  ushort* __restrict__ h){
  int node = blockIdx.x * 4 + (threadIdx.x >> 6);
  int lane = threadIdx.x & 63;
  const uint* xr = (const uint*)xb;
  uint self = xr[node * 64 + lane];
  float ax = bflo(self), ay = bfhi(self);
  int s = off4[node * 4], e = off4[node * 4 + 4];
  int j = s;
  for (; j + 8 <= e; j += 8){
    uint v0 = xr[csrc[j+0]*64+lane], v1 = xr[csrc[j+1]*64+lane];
    uint v2 = xr[csrc[j+2]*64+lane], v3 = xr[csrc[j+3]*64+lane];
    uint v4 = xr[csrc[j+4]*64+lane], v5 = xr[csrc[j+5]*64+lane];
    uint v6 = xr[csrc[j+6]*64+lane], v7 = xr[csrc[j+7]*64+lane];
    ax += bflo(v0)+bflo(v1)+bflo(v2)+bflo(v3)+bflo(v4)+bflo(v5)+bflo(v6)+bflo(v7);
    ay += bfhi(v0)+bfhi(v1)+bfhi(v2)+bfhi(v3)+bfhi(v4)+bfhi(v5)+bfhi(v6)+bfhi(v7);
  }
  for (; j + 4 <= e; j += 4){
    uint v0 = xr[csrc[j+0]*64+lane], v1 = xr[csrc[j+1]*64+lane];
    uint v2 = xr[csrc[j+2]*64+lane], v3 = xr[csrc[j+3]*64+lane];
    ax += bflo(v0)+bflo(v1)+bflo(v2)+bflo(v3);
    ay += bfhi(v0)+bfhi(v1)+bfhi(v2)+bfhi(v3);
  }
  for (; j < e; ++j){
    uint v = xr[csrc[j] * 64 + lane];
    ax += bflo(v); ay += bfhi(v);
  }
  uint o = (uint)f2bf(ax) | ((uint)f2bf(ay) << 16);
  ((uint*)h)[node * 64 + lane] = o;
}

// ---------------- aggregation, layers 1..3: bn23 affine+relu on the fly ----------------
__global__ __launch_bounds__(256) void agg_bn_kernel(const ushort* __restrict__ yb,
                                                     const int* __restrict__ off4,
                                                     const int* __restrict__ csrc,
                                                     const float* __restrict__ statsIn,
                                                     const float* __restrict__ g2,
                                                     const float* __restrict__ g3,
                                                     const float* __restrict__ b3,
                                                     ushort* __restrict__ h){
  __shared__ float sS[128];
  __shared__ float sT[128];
  bn_params_tid(statsIn, g2, g3, b3, 1, sS, sT);
  __syncthreads();
  int node = blockIdx.x * 4 + (threadIdx.x >> 6);
  int lane = threadIdx.x & 63;
  float S0 = sS[lane*2], T0 = sT[lane*2];
  float S1 = sS[lane*2+1], T1 = sT[lane*2+1];
  const uint* xr = (const uint*)yb;
  uint self = xr[node * 64 + lane];
  float ax = fmaxf(bflo(self)*S0+T0, 0.f), ay = fmaxf(bfhi(self)*S1+T1, 0.f);
  int s = off4[node * 4], e = off4[node * 4 + 4];
  int j = s;
  for (; j + 4 <= e; j += 4){
    uint v0 = xr[csrc[j+0]*64+lane], v1 = xr[csrc[j+1]*64+lane];
    uint v2 = xr[csrc[j+2]*64+lane], v3 = xr[csrc[j+3]*64+lane];
    ax += fmaxf(bflo(v0)*S0+T0,0.f) + fmaxf(bflo(v1)*S0+T0,0.f)
        + fmaxf(bflo(v2)*S0+T0,0.f) + fmaxf(bflo(v3)*S0+T0,0.f);
    ay += fmaxf(bfhi(v0)*S1+T1,0.f) + fmaxf(bfhi(v1)*S1+T1,0.f)
        + fmaxf(bfhi(v2)*S1+T1,0.f) + fmaxf(bfhi(v3)*S1+T1,0.f);
  }
  for (; j < e; ++j){
    uint v = xr[csrc[j] * 64 + lane];
    ax += fmaxf(bflo(v)*S0+T0,0.f);
    ay += fmaxf(bfhi(v)*S1+T1,0.f);
  }
  uint o = (uint)f2bf(ax) | ((uint)f2bf(ay) << 16);
  ((uint*)h)[node * 64 + lane] = o;
}

// ---------------- Gram: per-block partial G = A^T A and colsum s ----------------
// 256 blocks x 256 threads (4 waves). LDS transpose staging (32 rows/chunk),
// MFMA tiles: wave w owns I in {2w,2w+1}, J 0..7.
__global__ __launch_bounds__(256) void gram_kernel(const ushort* __restrict__ A,
                                                   float* __restrict__ Gpart,
                                                   float* __restrict__ spart){
  __shared__ ushort at[128 * 40];   // [col][40 rows], pad 40 -> 16B-aligned b128 reads
  __shared__ float scl[512];
  int t = threadIdx.x;
  int wave = t >> 6, lane = t & 63;
  int m = lane & 15, q = lane >> 4;
  int cp = t & 63;       // col-pair for staging
  int rsub = t >> 6;     // 0..3
  int rbase = blockIdx.x * GROWS;
  const uint* A32 = (const uint*)A;
  float sx = 0.f, sy = 0.f;
  f32x4 acc[2][8];
#pragma unroll
  for (int i = 0; i < 2; ++i)
#pragma unroll
    for (int j = 0; j < 8; ++j) acc[i][j] = (f32x4)0.f;

  for (int c0 = 0; c0 < GROWS; c0 += 32){
#pragma unroll
    for (int i = 0; i < 8; ++i){
      int rr = rsub * 8 + i;
      int r = rbase + c0 + rr;
      uint u = 0;
      if (r < NN && (c0 + rr) < GROWS) u = A32[r * 64 + cp];
      at[(2 * cp) * 40 + rr] = (ushort)(u & 0xffffu);
      at[(2 * cp + 1) * 40 + rr] = (ushort)(u >> 16);
      sx += bflo(u); sy += bfhi(u);
    }
    __syncthreads();
    short8 afr[2];
#pragma unroll
    for (int I = 0; I < 2; ++I){
      uint4 ta = *(const uint4*)&at[((2 * wave + I) * 16 + m) * 40 + q * 8];
      afr[I] = *(short8*)&ta;
    }
#pragma unroll
    for (int J = 0; J < 8; ++J){
      uint4 tb = *(const uint4*)&at[(J * 16 + m) * 40 + q * 8];
      short8 bfr = *(short8*)&tb;
      acc[0][J] = __builtin_amdgcn_mfma_f32_16x16x32_bf16(afr[0], bfr, acc[0][J], 0,0,0);
      acc[1][J] = __builtin_amdgcn_mfma_f32_16x16x32_bf16(afr[1], bfr, acc[1][J], 0,0,0);
    }
    __syncthreads();
  }

  float* gp = Gpart + blockIdx.x * 16384;
#pragma unroll
  for (int I = 0; I < 2; ++I){
#pragma unroll
    for (int J = 0; J < 8; ++J){
#pragma unroll
      for (int r = 0; r < 4; ++r){
        int row = (2 * wave + I) * 16 + q * 4 + r;
        int col = J * 16 + m;
        gp[row * 128 + col] = acc[I][J][r];
      }
    }
  }
  scl[(rsub * 64 + cp) * 2 + 0] = sx;
  scl[(rsub * 64 + cp) * 2 + 1] = sy;
  __syncthreads();
  if (t < 64){
    float ax = scl[t*2] + scl[(64+t)*2] + scl[(128+t)*2] + scl[(192+t)*2];
    float ay = scl[t*2+1] + scl[(64+t)*2+1] + scl[(128+t)*2+1] + scl[(192+t)*2+1];
    spart[blockIdx.x * 128 + 2*t] = ax;
    spart[blockIdx.x * 128 + 2*t + 1] = ay;
  }
}

__global__ void gram_reduce(const float* __restrict__ Gpart, const float* __restrict__ spart,
                            float* __restrict__ G, float* __restrict__ svec){
  int id = blockIdx.x * 256 + threadIdx.x;
  if (id < 16384){
    float a = 0.f;
    for (int p = 0; p < GBLK; ++p) a += Gpart[p * 16384 + id];
    G[id] = a;
  } else if (id < 16512){
    int c = id - 16384;
    float a = 0.f;
    for (int p = 0; p < GBLK; ++p) a += spart[p * 128 + c];
    svec[c] = a;
  }
}

// ---------------- analytic bn1 params: per-block one output column ----------------
__global__ __launch_bounds__(256) void param1_kernel(const float* __restrict__ G,
                                                     const float* __restrict__ svec,
                                                     const ushort* __restrict__ W1b,
                                                     const float* __restrict__ g1,
                                                     const float* __restrict__ bb1,
                                                     float* __restrict__ params1){
  __shared__ float wf[128];
  __shared__ float red[256];
  int c = blockIdx.x, t = threadIdx.x;
  const uint* w32 = (const uint*)W1b + c * 64;
  if (t < 64){ uint u = w32[t]; wf[2*t] = bflo(u); wf[2*t+1] = bfhi(u); }
  __syncthreads();
  float acc = 0.f;
  for (int idx = t; idx < 16384; idx += 256)
    acc += G[idx] * wf[idx >> 7] * wf[idx & 127];
  red[t] = acc;
  __syncthreads();
  for (int o = 128; o > 0; o >>= 1){ if (t < o) red[t] += red[t + o]; __syncthreads(); }
  float qq = red[0];
  __syncthreads();
  red[t] = (t < 128) ? wf[t] * svec[t] : 0.f;
  __syncthreads();
  for (int o = 128; o > 0; o >>= 1){ if (t < o) red[t] += red[t + o]; __syncthreads(); }
  if (t == 0){
    const float invN = 1.f / (float)NN;
    float meanZ = red[0] * invN;                 // mean of (y - b)
    float var = fmaxf(qq * invN - meanZ * meanZ, 0.f);
    float S = g1[c] * rsqrtf(var + BN_EPS);
    params1[c] = S;
    params1[128 + c] = bb1[c] - meanZ * S;       // T' folds bias b1
  }
}

// ---------------- fused MLP: fc1 -> bn1(analytic)+relu -> fc2 -> stats2 -> y2b ----------------
// 391 blocks x 512 threads (8 waves, 1 tile each). Dynamic LDS 71680 B:
// w1 (34816, aliased as repack scratch after fc1) | w2 (34816) | sS/sT/ssum/ssq (2048).
__global__ __launch_bounds__(512) void fused_mlp(const ushort* __restrict__ hb,
                                                 const ushort* __restrict__ w1g,
                                                 const ushort* __restrict__ w2g,
                                                 const float* __restrict__ b2v,
                                                 const float* __restrict__ params1,
                                                 float* __restrict__ statsOut,
                                                 ushort* __restrict__ y2b){
  extern __shared__ char dyn[];
  uint4* w1 = (uint4*)dyn;
  uint4* w2 = (uint4*)(dyn + 34816);
  float* sS = (float*)(dyn + 69632);
  float* sT = sS + 128;
  float* ssum = sT + 128;
  float* ssq = ssum + 128;
  int t = threadIdx.x, wave = t >> 6, lane = t & 63;
  int m = lane & 15, q = lane >> 4;
  int tile = blockIdx.x * 8 + wave;
  bool tv = tile < NTILES;
  const uint4* W1g = (const uint4*)w1g;
  const uint4* W2g = (const uint4*)w2g;
  for (int c = t; c < 2048; c += 512){
    int d = (c >> 4) * 17 + (c & 15);
    w1[d] = W1g[c];
    w2[d] = W2g[c];
  }
  if (t < 128){
    sS[t] = params1[t]; sT[t] = params1[128 + t];
    ssum[t] = 0.f; ssq[t] = 0.f;
  }
  __syncthreads();

  short8 af[4];
  if (tv){
    const uint4* A4 = (const uint4*)hb;
#pragma unroll
    for (int kt = 0; kt < 4; ++kt){
      uint4 tt = A4[(tile * 16 + m) * 16 + kt * 4 + q];
      af[kt] = *(short8*)&tt;
    }
  }

  f32x4 acc[8];
#pragma unroll
  for (int i = 0; i < 8; ++i) acc[i] = (f32x4)0.f;
  if (tv){
#pragma unroll
    for (int kt = 0; kt < 4; ++kt){
#pragma unroll
      for (int to = 0; to < 8; ++to){
        uint4 bw = w1[(to*16+m)*17 + kt*4 + q];
        acc[to] = __builtin_amdgcn_mfma_f32_16x16x32_bf16(af[kt], *(short8*)&bw, acc[to], 0,0,0);
      }
    }
  }
  __syncthreads();   // all waves done reading w1 before scratch aliasing

  uint* myscr = ((uint*)w1) + wave * 1088;  // 16 rows x 68 uints, wave-private
  if (tv){
#pragma unroll
    for (int to = 0; to < 8; ++to){
      int col = to * 16 + m;
      float S = sS[col], T = sT[col];
#pragma unroll
      for (int r = 0; r < 4; ++r){
        float v = fmaxf(acc[to][r] * S + T, 0.f);   // bias b1 folded into T
        uint u = f2bf(v);
        uint other = (uint)__shfl_xor((int)u, 1);
        if (!(m & 1)) myscr[(q*4+r)*68 + to*8 + (m>>1)] = u | (other << 16);
      }
    }
#pragma unroll
    for (int kt = 0; kt < 4; ++kt){
      uint4 tt = *(const uint4*)(myscr + m * 68 + kt * 16 + q * 4);
      af[kt] = *(short8*)&tt;
    }
  }

#pragma unroll
  for (int i = 0; i < 8; ++i) acc[i] = (f32x4)0.f;
  if (tv){
#pragma unroll
    for (int kt = 0; kt < 4; ++kt){
#pragma unroll
      for (int to = 0; to < 8; ++to){
        uint4 bw = w2[(to*16+m)*17 + kt*4 + q];
        acc[to] = __builtin_amdgcn_mfma_f32_16x16x32_bf16(af[kt], *(short8*)&bw, acc[to], 0,0,0);
      }
    }
#pragma unroll
    for (int to = 0; to < 8; ++to){
      float bc = b2v[to*16+m];
#pragma unroll
      for (int r = 0; r < 4; ++r) acc[to][r] += bc;
    }
  }

#pragma unroll
  for (int to = 0; to < 8; ++to){
    float ls = 0.f, lq = 0.f;
    if (tv){
#pragma unroll
      for (int r = 0; r < 4; ++r){ float v = acc[to][r]; ls += v; lq += v*v; }
    }
    ls += __shfl_xor(ls, 16); lq += __shfl_xor(lq, 16);
    ls += __shfl_xor(ls, 32); lq += __shfl_xor(lq, 32);
    if (tv && q == 0){ atomicAdd(&ssum[to*16+m], ls); atomicAdd(&ssq[to*16+m], lq); }
  }
  __syncthreads();
  if (t < 128){
    atomicAdd(&statsOut[t], ssum[t]);
    atomicAdd(&statsOut[128 + t], ssq[t]);
  }
  if (tv){
#pragma unroll
    for (int to = 0; to < 8; ++to){
      int col = to * 16 + m;
#pragma unroll
      for (int r = 0; r < 4; ++r){
        int row = tile * 16 + q * 4 + r;
        y2b[row * 128 + col] = __builtin_bit_cast(ushort, f2bf(acc[to][r]));
      }
    }
  }
}

// ---------------- classifier GEMM: relu(bn23(A)) @ Wf^T + b -> f32 ----------------
__global__ __launch_bounds__(512) void gemm_cls(const ushort* __restrict__ A,
                                                const ushort* __restrict__ W,
                                                const float* __restrict__ bias,
                                                float* __restrict__ Yf,
                                                const float* __restrict__ statsIn,
                                                const float* __restrict__ gA,
                                                const float* __restrict__ gB,
                                                const float* __restrict__ bB){
  __shared__ uint4 w4[128 * 17];
  __shared__ float sS[128];
  __shared__ float sT[128];
  const uint4* Wg = (const uint4*)W;
  for (int c = threadIdx.x; c < 2048; c += 512){
    w4[(c >> 4) * 17 + (c & 15)] = Wg[c];
  }
  bn_params_tid(statsIn, gA, gB, bB, 1, sS, sT);
  __syncthreads();

  int wave = threadIdx.x >> 6;
  int lane = threadIdx.x & 63;
  int m = lane & 15, q = lane >> 4;
  int tile = blockIdx.x * 8 + wave;
  bool tv = tile < NTILES;
  const uint4* A4 = (const uint4*)A;

  f32x4 acc[8];
#pragma unroll
  for (int i = 0; i < 8; ++i) acc[i] = (f32x4)0.f;

#pragma unroll
  for (int kt = 0; kt < 4; ++kt){
    short8 af = (short8)0;
    if (tv){
      uint4 tt = A4[(tile * 16 + m) * 16 + kt * 4 + q];
      int kc = kt * 32 + q * 8;
      uint4 pk;
      pk.x = (uint)f2bf(fmaxf(bflo(tt.x)*sS[kc+0]+sT[kc+0],0.f))
           | ((uint)f2bf(fmaxf(bfhi(tt.x)*sS[kc+1]+sT[kc+1],0.f)) << 16);
      pk.y = (uint)f2bf(fmaxf(bflo(tt.y)*sS[kc+2]+sT[kc+2],0.f))
           | ((uint)f2bf(fmaxf(bfhi(tt.y)*sS[kc+3]+sT[kc+3],0.f)) << 16);
      pk.z = (uint)f2bf(fmaxf(bflo(tt.z)*sS[kc+4]+sT[kc+4],0.f))
           | ((uint)f2bf(fmaxf(bfhi(tt.z)*sS[kc+5]+sT[kc+5],0.f)) << 16);
      pk.w = (uint)f2bf(fmaxf(bflo(tt.w)*sS[kc+6]+sT[kc+6],0.f))
           | ((uint)f2bf(fmaxf(bfhi(tt.w)*sS[kc+7]+sT[kc+7],0.f)) << 16);
      af = *(short8*)&pk;
    }
#pragma unroll
    for (int to = 0; to < 8; ++to){
      uint4 bw = w4[(to * 16 + m) * 17 + kt * 4 + q];
      acc[to] = __builtin_amdgcn_mfma_f32_16x16x32_bf16(af, *(short8*)&bw, acc[to], 0, 0, 0);
    }
  }

  if (tv){
#pragma unroll
    for (int to = 0; to < 8; ++to){
      int col = to * 16 + m;
      float bc = bias[col];
#pragma unroll
      for (int r = 0; r < 4; ++r)
        Yf[(tile * 16 + q * 4 + r) * 128 + col] = acc[to][r] + bc;
    }
  }
}

extern "C" void kernel_launch(void* const* d_in, const int* in_sizes, int n_in,
                              void* d_out, int out_size, void* d_ws, size_t ws_size,
                              hipStream_t stream) {
  const float* x     = (const float*)d_in[0];
  const int*   ei    = (const int*)d_in[1];
  const float* fc1_w = (const float*)d_in[2];
  const float* fc1_b = (const float*)d_in[3];  // folded analytically (mean includes b1)
  const float* bn1_g = (const float*)d_in[4];
  const float* bn1_b = (const float*)d_in[5];
  const float* fc2_w = (const float*)d_in[6];
  const float* fc2_b = (const float*)d_in[7];
  const float* bn2_g = (const float*)d_in[8];
  const float* bn3_g = (const float*)d_in[10];
  const float* bn3_b = (const float*)d_in[11];
  const float* fc_w  = (const float*)d_in[12];
  const float* fc_b  = (const float*)d_in[13];
  (void)fc1_b;  // b1 cancels in var and is folded via meanZ (see param1_kernel)

  int E = in_sizes[1] / 2;
  const int* srcp = ei;
  const int* dstp = ei + E;

  char* ws = (char*)d_ws;
  int*    off4    = (int*)(ws + 0);            // 4N+1 ints
  int*    cnt4    = (int*)(ws + 3200064);      // 4N ints
  int*    pos     = (int*)(ws + 6400064);      // E ints
  int*    csrc    = (int*)(ws + 9600064);      // E ints (aliased `incl` pre-fill2)
  ushort* wb      = (ushort*)(ws + 12800064);  // 147456 bf16
  float*  stats   = (float*)(ws + 13094976);   // 4 layers x 256
  int*    sscr    = (int*)(ws + 13099072);     // scan bsum/base
  float*  params1 = (float*)(ws + 13103168);   // 256
  float*  G       = (float*)(ws + 13104192);   // 16384
  float*  svec    = (float*)(ws + 13169728);   // 128
  float*  Gpart   = (float*)(ws + 13170240);   // 256 x 16384
  float*  spart   = (float*)(ws + 29947456);   // 256 x 128
  ushort* xb      = (ushort*)(ws + 30078528);  // N*128 bf16
  ushort* hb      = (ushort*)(ws + 42878528);  // N*128 bf16
  ushort* y2b     = (ushort*)(ws + 55678528);  // N*128 bf16

  int* incl = csrc;
  int* bsum = sscr;
  int* base = sscr + 512;

  hipMemsetAsync(cnt4, 0, 3200000, stream);
  hipMemsetAsync(stats, 0, 4096, stream);

  cast_f32_bf16x4<<<2048, 256, 0, stream>>>(x, xb, NN * HD / 4);
  cast_weights<<<144, 256, 0, stream>>>(fc1_w, fc2_w, fc_w, wb);

  const int EB4 = (E / 4 + 255) / 256 + 1;
  const int SB4 = (N4 + 1023) / 1024;   // 196
  fill1_kernel<<<EB4, 256, 0, stream>>>(dstp, cnt4, pos, E);
  scan1_kernel<<<SB4, 1024, 0, stream>>>(cnt4, incl, bsum, N4);
  scan2_kernel<<<1, 64, 0, stream>>>(bsum, base, off4, SB4, N4);
  scan3_kernel<<<SB4, 1024, 0, stream>>>(cnt4, incl, base, off4, N4);
  fill2_kernel<<<EB4, 256, 0, stream>>>(srcp, dstp, off4, pos, csrc, E);

  hipFuncSetAttribute((const void*)fused_mlp,
                      hipFuncAttributeMaxDynamicSharedMemorySize, 71680);

  const int gb = (NTILES + 7) / 8;   // 391

  for (int L = 0; L < NL; ++L){
    if (L == 0){
      agg_kernel<<<NN / 4, 256, 0, stream>>>(xb, off4, csrc, hb);
    } else {
      agg_bn_kernel<<<NN / 4, 256, 0, stream>>>(y2b, off4, csrc,
                                                stats + (L - 1) * 256,
                                                bn2_g + (L - 1) * 128,
                                                bn3_g + (L - 1) * 128,
                                                bn3_b + (L - 1) * 128, hb);
    }
    gram_kernel<<<GBLK, 256, 0, stream>>>(hb, Gpart, spart);
    gram_reduce<<<65, 256, 0, stream>>>(Gpart, spart, G, svec);
    param1_kernel<<<128, 256, 0, stream>>>(G, svec, wb + L * 16384,
                                           bn1_g + L * 128, bn1_b + L * 128, params1);
    fused_mlp<<<gb, 512, 71680, stream>>>(hb, wb + L * 16384, wb + 65536 + L * 16384,
                                          fc2_b + L * 128, params1,
                                          stats + L * 256, y2b);
  }

  gemm_cls<<<gb, 512, 0, stream>>>(y2b, wb + 131072, fc_b, (float*)d_out,
                                   stats + 3 * 256, bn2_g + 384,
                                   bn3_g + 384, bn3_b + 384);
}